// Round 5
// baseline (471.597 us; speedup 1.0000x reference)
//
#include <hip/hip_runtime.h>

#define Bn   32
#define Cn   17
#define Hn   96
#define Wn   72
#define Kn   3
#define KKn  9
#define PADn 1
#define HWn  (Hn * Wn)            // 6912
#define TPB  576                  // 9 waves
#define PX_PER_THREAD 4
#define PX_PER_BLOCK (TPB * PX_PER_THREAD)   // 2304 = 32 rows
#define NBLK_X (HWn / PX_PER_BLOCK)          // 3

// LDS swizzle: +1 float of pad per 32 floats -> stride-4 gathers cover all 32 banks
#define SWZ(i) ((i) + ((i) >> 5))
#define XS_SIZE (HWn + HWn / 32)  // 7128 floats = 28512 B

__global__ __launch_bounds__(TPB) void deform_conv_kernel(
    const float* __restrict__ x,
    const float* __restrict__ offsets,
    const float* __restrict__ mask,
    const float* __restrict__ weight,
    const float* __restrict__ bias,
    float* __restrict__ out)
{
    __shared__ float xs[XS_SIZE];

    const int tid = threadIdx.x;
    const int bc  = blockIdx.y;              // b*C + c
    const int c   = bc % Cn;

    // ---- stage full x plane into LDS (float4 global loads, swizzled b32 writes) ----
    {
        const float4* __restrict__ xp4 = (const float4*)(x + (size_t)bc * HWn);
        #pragma unroll
        for (int j = 0; j < HWn / 4 / TPB; ++j) {   // 3 iters
            const int ci = j * TPB + tid;           // float4 chunk index
            const float4 v = xp4[ci];
            const int i = ci * 4;                   // i % 32 in {0,4,...,28}: no pad crossing
            const int s = SWZ(i);
            xs[s + 0] = v.x; xs[s + 1] = v.y; xs[s + 2] = v.z; xs[s + 3] = v.w;
        }
    }
    __syncthreads();

    // ---- 4 consecutive pixels per thread (row-aligned: 72 % 4 == 0) ----
    const int hw = blockIdx.x * PX_PER_BLOCK + tid * PX_PER_THREAD;
    const int h  = hw / Wn;
    const int w  = hw - h * Wn;

    const float* __restrict__ offp = offsets + (size_t)bc * (KKn * 2 * HWn) + hw;
    const float* __restrict__ mp   = mask    + (size_t)bc * (KKn * HWn) + hw;
    const float* __restrict__ wp   = weight  + c * KKn;   // block-uniform -> scalar loads

    const float bv = bias[c];
    float acc[PX_PER_THREAD] = {bv, bv, bv, bv};

    // ---- software pipeline: prefetch kk+1's loads before computing kk ----
    float4 dy4 = *(const float4*)(offp + 0 * HWn);
    float4 dx4 = *(const float4*)(offp + 1 * HWn);
    float4 m4  = *(const float4*)(mp   + 0 * HWn);

    #pragma unroll
    for (int kk = 0; kk < KKn; ++kk) {
        float4 ndy, ndx, nm;
        if (kk < KKn - 1) {
            ndy = *(const float4*)(offp + (size_t)(kk * 2 + 2) * HWn);
            ndx = *(const float4*)(offp + (size_t)(kk * 2 + 3) * HWn);
            nm  = *(const float4*)(mp   + (size_t)(kk + 1) * HWn);
        }

        const float wk = wp[kk];
        const int ky = kk / Kn;
        const int kx = kk - ky * Kn;
        const float base_y = (float)(h - PADn + ky);

        #pragma unroll
        for (int p = 0; p < PX_PER_THREAD; ++p) {
            const float dy = ((const float*)&dy4)[p];
            const float dx = ((const float*)&dx4)[p];
            const float m  = ((const float*)&m4)[p];

            const float py = base_y + dy;
            const float px = (float)(w + p - PADn + kx) + dx;

            const float y0f = floorf(py);
            const float x0f = floorf(px);
            const float wy  = py - y0f;
            const float wx  = px - x0f;
            const int y0 = (int)y0f;
            const int x0 = (int)x0f;
            const int y1 = y0 + 1;
            const int x1 = x0 + 1;

            const int y0c = min(max(y0, 0), Hn - 1);
            const int y1c = min(max(y1, 0), Hn - 1);
            const int x0c = min(max(x0, 0), Wn - 1);
            const int x1c = min(max(x1, 0), Wn - 1);

            const float wy0 = (y0 == y0c) ? (1.f - wy) : 0.f;
            const float wy1 = (y1 == y1c) ? wy         : 0.f;
            const float wx0 = (x0 == x0c) ? (1.f - wx) : 0.f;
            const float wx1 = (x1 == x1c) ? wx         : 0.f;

            const int r0 = y0c * Wn;
            const int r1 = y1c * Wn;
            const float v00 = xs[SWZ(r0 + x0c)];
            const float v01 = xs[SWZ(r0 + x1c)];
            const float v10 = xs[SWZ(r1 + x0c)];
            const float v11 = xs[SWZ(r1 + x1c)];

            const float row0 = v00 * wx0 + v01 * wx1;
            const float row1 = v10 * wx0 + v11 * wx1;
            const float v    = row0 * wy0 + row1 * wy1;

            acc[p] += v * (m * wk);
        }

        dy4 = ndy; dx4 = ndx; m4 = nm;
    }

    float4 o;
    o.x = acc[0]; o.y = acc[1]; o.z = acc[2]; o.w = acc[3];
    *(float4*)(out + (size_t)bc * HWn + hw) = o;
}

extern "C" void kernel_launch(void* const* d_in, const int* in_sizes, int n_in,
                              void* d_out, int out_size, void* d_ws, size_t ws_size,
                              hipStream_t stream) {
    const float* x       = (const float*)d_in[0];
    const float* offsets = (const float*)d_in[1];
    const float* mask    = (const float*)d_in[2];
    const float* weight  = (const float*)d_in[3];
    const float* bias    = (const float*)d_in[4];
    float* out = (float*)d_out;

    dim3 block(TPB, 1, 1);
    dim3 grid(NBLK_X, Bn * Cn, 1);
    deform_conv_kernel<<<grid, block, 0, stream>>>(x, offsets, mask, weight, bias, out);
}

// Round 6
// 457.323 us; speedup vs baseline: 1.0312x; 1.0312x over previous
//
#include <hip/hip_runtime.h>

#define Bn   32
#define Cn   17
#define Hn   96
#define Wn   72
#define Kn   3
#define KKn  9
#define PADn 1
#define HWn  (Hn * Wn)            // 6912
#define TPB  576                  // 9 waves
#define ROWS_PER_BLOCK 32
#define NBLK_X (Hn / ROWS_PER_BLOCK)   // 3
#define NPX  4                    // pixels/thread, strided by 8 rows

// padded LDS image: rows -1..97 (99), cols -1..73 (75); index (y+1)*75 + (x+1)
#define PSTR 75
#define PROWS 99
#define XS_SIZE (PROWS * PSTR)    // 7425 floats = 29.7 KB

__global__ __launch_bounds__(TPB) void deform_conv_kernel(
    const float* __restrict__ x,
    const float* __restrict__ offsets,
    const float* __restrict__ mask,
    const float* __restrict__ weight,
    const float* __restrict__ bias,
    float* __restrict__ out)
{
    __shared__ float xs[XS_SIZE];

    const int tid = threadIdx.x;
    const int bc  = blockIdx.y;              // b*C + c
    const int c   = bc % Cn;

    // ---- zero the padded plane (guard border must be 0) ----
    for (int i = tid; i < XS_SIZE; i += TPB) xs[i] = 0.f;
    __syncthreads();

    // ---- stage interior (float4 global loads; 72%4==0 so chunks stay in-row) ----
    {
        const float4* __restrict__ xp4 = (const float4*)(x + (size_t)bc * HWn);
        #pragma unroll
        for (int j = 0; j < HWn / 4 / TPB; ++j) {   // 3 iters
            const int ci  = j * TPB + tid;
            const float4 v = xp4[ci];
            const int idx = ci * 4;
            const int y = idx / Wn;
            const int xcol = idx - y * Wn;
            float* d = &xs[(y + 1) * PSTR + (xcol + 1)];
            d[0] = v.x; d[1] = v.y; d[2] = v.z; d[3] = v.w;
        }
    }
    __syncthreads();

    // ---- thread map: lanes w-consecutive; 4 px per thread strided by 8 rows ----
    const int w  = tid % Wn;
    const int h0 = blockIdx.x * ROWS_PER_BLOCK + tid / Wn;   // tid/Wn in [0,8)
    const int hw0 = h0 * Wn + w;

    const float* __restrict__ offp = offsets + (size_t)bc * (KKn * 2 * HWn);
    const float* __restrict__ mp   = mask    + (size_t)bc * (KKn * HWn);
    const float* __restrict__ wp   = weight  + c * KKn;   // block-uniform -> scalar

    const float bv = bias[c];
    float acc[NPX] = {bv, bv, bv, bv};

    const float wf = (float)w;
    float hpf[NPX];
    #pragma unroll
    for (int p = 0; p < NPX; ++p) hpf[p] = (float)(h0 + 8 * p);

    #pragma unroll
    for (int kk = 0; kk < KKn; ++kk) {
        const float wk  = wp[kk];
        const int   ky  = kk / Kn;
        const int   kx  = kk - ky * Kn;
        const float kyo = (float)(ky - PADn);
        const float kxo = (float)(kx - PADn);

        // coalesced scalar streaming loads (issue all 12 first)
        float dyv[NPX], dxv[NPX], mv[NPX];
        #pragma unroll
        for (int p = 0; p < NPX; ++p) {
            const int hw_p = hw0 + p * 8 * Wn;
            dyv[p] = offp[(size_t)(kk * 2 + 0) * HWn + hw_p];
            dxv[p] = offp[(size_t)(kk * 2 + 1) * HWn + hw_p];
            mv[p]  = mp[(size_t)kk * HWn + hw_p];
        }

        #pragma unroll
        for (int p = 0; p < NPX; ++p) {
            // clamp to [-1, H] / [-1, W]: outside that, contribution is exactly 0,
            // and at the clamp point the surviving corner weight is 0 (guard zeros
            // absorb the invalid corners).
            float py = hpf[p] + (dyv[p] + kyo);
            float px = wf     + (dxv[p] + kxo);
            py = fminf(fmaxf(py, -1.f), (float)Hn);
            px = fminf(fmaxf(px, -1.f), (float)Wn);

            const float y0f = floorf(py);
            const float x0f = floorf(px);
            const float wy  = py - y0f;
            const float wx  = px - x0f;
            const int y0 = (int)y0f;                 // in [-1, 96]
            const int x0 = (int)x0f;                 // in [-1, 72]

            const float* pr = &xs[(y0 + 1) * PSTR + (x0 + 1)];
            const float v00 = pr[0];
            const float v01 = pr[1];
            const float v10 = pr[PSTR];
            const float v11 = pr[PSTR + 1];

            const float top = v00 + wx * (v01 - v00);
            const float bot = v10 + wx * (v11 - v10);
            const float v   = top + wy * (bot - top);

            acc[p] += v * (mv[p] * wk);
        }
    }

    const size_t ob = (size_t)bc * HWn;
    #pragma unroll
    for (int p = 0; p < NPX; ++p)
        out[ob + hw0 + p * 8 * Wn] = acc[p];
}

extern "C" void kernel_launch(void* const* d_in, const int* in_sizes, int n_in,
                              void* d_out, int out_size, void* d_ws, size_t ws_size,
                              hipStream_t stream) {
    const float* x       = (const float*)d_in[0];
    const float* offsets = (const float*)d_in[1];
    const float* mask    = (const float*)d_in[2];
    const float* weight  = (const float*)d_in[3];
    const float* bias    = (const float*)d_in[4];
    float* out = (float*)d_out;

    dim3 block(TPB, 1, 1);
    dim3 grid(NBLK_X, Bn * Cn, 1);
    deform_conv_kernel<<<grid, block, 0, stream>>>(x, offsets, mask, weight, bias, out);
}